// Round 11
// baseline (811.750 us; speedup 1.0000x reference)
//
#include <hip/hip_runtime.h>
#include <math.h>

#define NFEAT 512
#define NHID  256
#define NCLASS 40
#define NBUCK 782        // ceil(100000 / 128) dst-buckets of 128 nodes
#define BCAP  5120       // bucket capacity: mean 4096 + ~16 sigma
#define PCHUNK 8192      // edges per partition block (LDS-staged)

typedef __attribute__((ext_vector_type(8))) short short8;
typedef __attribute__((ext_vector_type(4))) float f32x4;

// ---------------- bf16 helpers ----------------

__device__ __forceinline__ float bflo(unsigned u) {
    union { unsigned i; float f; } x; x.i = u << 16; return x.f;
}
__device__ __forceinline__ float bfhi(unsigned u) {
    union { unsigned i; float f; } x; x.i = u & 0xffff0000u; return x.f;
}
__device__ __forceinline__ unsigned short f2bf(float f) {
    union { float f; unsigned i; } x; x.f = f;
    unsigned r = x.i + 0x7fffu + ((x.i >> 16) & 1u);   // round-to-nearest-even
    return (unsigned short)(r >> 16);
}
__device__ __forceinline__ float bf2f(unsigned short h) {
    union { unsigned i; float f; } x; x.i = (unsigned)h << 16; return x.f;
}
__device__ __forceinline__ unsigned pack2(float a, float b) {
    return (unsigned)f2bf(a) | ((unsigned)f2bf(b) << 16);
}

// ---------------- fused: W1 cast (blocks 0..511) ∥ W2 hi/lo cast (block 512) ∥
// LDS-staged edge partition (rest).
// Partition: hist -> block scan -> bucket-major LDS staging -> per-bucket global
// reservation -> wave-per-bucket coalesced flush. Entry: (src<<7)|(dst&127).

__global__ __launch_bounds__(256) void partcast_k(const float* __restrict__ W1,
                                                  unsigned short* __restrict__ WT,
                                                  const float* __restrict__ W2,
                                                  unsigned short* __restrict__ WT2,
                                                  const int* __restrict__ ei,
                                                  int* bucketCnt,
                                                  unsigned* __restrict__ binned, int E) {
    __shared__ unsigned staged[PCHUNK];
    __shared__ int hist[NBUCK];
    __shared__ int lofs[NBUCK];
    __shared__ int sbase[NBUCK];
    __shared__ int lcur[NBUCK];
    __shared__ int wsum[256];
    int bid = blockIdx.x;
    int t = threadIdx.x;
    if (bid < (NFEAT * NHID) / 256) {
        int idx = bid * 256 + t;
        int k = idx >> 8;
        int nn = idx & 255;
        WT[(size_t)nn * NFEAT + k] = f2bf(W1[idx]);
        return;
    }
    if (bid == (NFEAT * NHID) / 256) {
        // W2 -> col-major bf16 hi/lo split: WT2[j][k] (j<48 hi, j>=48 lo), 48 cols padded
        for (int idx = t; idx < 96 * 256; idx += 256) {
            int j2 = idx >> 8;           // 0..95
            int k = idx & 255;
            int j = (j2 < 48) ? j2 : j2 - 48;
            float v = (j < NCLASS) ? W2[k * NCLASS + j] : 0.f;
            unsigned short hi = f2bf(v);
            WT2[idx] = (j2 < 48) ? hi : f2bf(v - bf2f(hi));
        }
        return;
    }
    int pb = bid - (NFEAT * NHID) / 256 - 1;
    int beg = pb * PCHUNK;
    int end = beg + PCHUNK; if (end > E) end = E;

    for (int b = t; b < NBUCK; b += 256) hist[b] = 0;
    __syncthreads();
    // phase 1: histogram
    for (int e = beg + t; e < end; e += 256) {
        int d = ei[(size_t)E + e];
        atomicAdd(&hist[d >> 7], 1);
    }
    __syncthreads();
    // phase 2: exclusive scan over 782 bucket counts (256 threads x 4)
    int v[4];
    int s0 = 0;
#pragma unroll
    for (int r = 0; r < 4; ++r) {
        int idx = t * 4 + r;
        v[r] = (idx < NBUCK) ? hist[idx] : 0;
        s0 += v[r];
    }
    wsum[t] = s0;
    __syncthreads();
    for (int off = 1; off < 256; off <<= 1) {
        int add = (t >= off) ? wsum[t - off] : 0;
        __syncthreads();
        wsum[t] += add;
        __syncthreads();
    }
    int excl = wsum[t] - s0;
#pragma unroll
    for (int r = 0; r < 4; ++r) {
        int idx = t * 4 + r;
        if (idx < NBUCK) { lofs[idx] = excl; lcur[idx] = excl; }
        excl += v[r];
    }
    __syncthreads();
    // phase 3a: global reservation per bucket
    for (int b = t; b < NBUCK; b += 256) {
        int h = hist[b];
        if (h) sbase[b] = atomicAdd(&bucketCnt[b], h);
    }
    // phase 3b: re-read chunk (L2-warm), scatter bucket-major into LDS
    for (int e = beg + t; e < end; e += 256) {
        int s = ei[e];
        int d = ei[(size_t)E + e];
        int b = d >> 7;
        int p = atomicAdd(&lcur[b], 1);
        staged[p] = ((unsigned)s << 7) | (unsigned)(d & 127);
    }
    __syncthreads();
    // phase 4: coalesced flush, wave-per-bucket round-robin
    int w = t >> 6, lane = t & 63;
    for (int b = w; b < NBUCK; b += 4) {
        int h = hist[b];
        if (!h) continue;
        int lo = lofs[b];
        size_t gb = (size_t)b * BCAP + sbase[b];
        for (int l = lane; l < h; l += 64)
            binned[gb + l] = staged[lo + l];
    }
}

// ---------------- exclusive scan over 782 bucket counts -> bucket bases ----------------

__global__ __launch_bounds__(1024) void bscan_k(const int* __restrict__ bucketCnt,
                                                int* __restrict__ bbase,
                                                int* __restrict__ offs, int n, int E) {
    __shared__ int sd[1024];
    int t = threadIdx.x;
    int v = (t < NBUCK) ? bucketCnt[t] : 0;
    sd[t] = v;
    __syncthreads();
    for (int off = 1; off < 1024; off <<= 1) {
        int add = (t >= off) ? sd[t - off] : 0;
        __syncthreads();
        sd[t] += add;
        __syncthreads();
    }
    if (t < NBUCK) bbase[t] = sd[t] - v;
    if (t == 0) offs[n] = E;
}

// ---------------- bucket-local CSR fill: per-node hist + scan + offs + dis + scatter ----

__global__ __launch_bounds__(512) void fill2_k(const unsigned* __restrict__ binned,
                                               const int* __restrict__ bucketCnt,
                                               const int* __restrict__ bbase,
                                               int* __restrict__ offs,
                                               float* __restrict__ dis,
                                               int* __restrict__ csrs, int n) {
    __shared__ int h128[128];
    __shared__ int sd[128];
    __shared__ int lcur[128];
    int b = blockIdx.x;
    int t = threadIdx.x;
    int node0 = b << 7;
    int cbt = bucketCnt[b];
    size_t base_in = (size_t)b * BCAP;
    int gbase = bbase[b];
    if (t < 128) h128[t] = 0;
    __syncthreads();
    for (int e = t; e < cbt; e += 512) {
        unsigned u = binned[base_in + e];
        atomicAdd(&h128[u & 127], 1);
    }
    __syncthreads();
    int v = (t < 128) ? h128[t] : 0;
    if (t < 128) sd[t] = v;
    __syncthreads();
    for (int off = 1; off < 128; off <<= 1) {
        int add = (t < 128 && t >= off) ? sd[t - off] : 0;
        __syncthreads();
        if (t < 128) sd[t] += add;
        __syncthreads();
    }
    if (t < 128) {
        int excl = sd[t] - v;
        int nd = node0 + t;
        if (nd < n) {
            offs[nd] = gbase + excl;
            dis[nd] = rsqrtf((float)v + 1.0f);   // +1 self loop
        }
        lcur[t] = gbase + excl;
    }
    __syncthreads();
    for (int e = t; e < cbt; e += 512) {
        unsigned u = binned[base_in + e];
        int pos = atomicAdd(&lcur[u & 127], 1);
        csrs[pos] = (int)(u >> 7);
    }
}

// ---------------- GEMM1 (LDS-free): H'(bf16) = dis[i] * (X fp32→bf16 · W1), MFMA -------
// 128 rows x 256 cols per block, 512 threads = 8 waves (2M x 4N), 64x64 per wave.
// A fragments: 2x float4 from X row, packed to bf16 per lane (VALU overlaps MFMA pipe).
// B fragments: 16-B direct loads from WT (L2-resident, fragment-layout-friendly).
// No LDS, no barriers; occupancy VGPR-bound.

__global__ __launch_bounds__(512) void gemm1_k(const float* __restrict__ X,
                                               const unsigned short* __restrict__ WT,
                                               const float* __restrict__ dis,
                                               unsigned short* __restrict__ H, int M) {
    int t = threadIdx.x;
    int lane = t & 63;
    int w = t >> 6;          // 0..7
    int wm = w >> 2;         // 0..1
    int wn = w & 3;          // 0..3
    int m0 = blockIdx.x * 128 + wm * 64;
    int quad = lane >> 4;
    int r16 = lane & 15;

    f32x4 acc[4][4];
#pragma unroll
    for (int a = 0; a < 4; ++a)
#pragma unroll
        for (int b = 0; b < 4; ++b) acc[a][b] = (f32x4){0.f, 0.f, 0.f, 0.f};

    const unsigned short* wbase = WT + (size_t)(wn * 64 + r16) * NFEAT + quad * 8;
    const float* abase[4];
    bool okA[4];
#pragma unroll
    for (int sm = 0; sm < 4; ++sm) {
        int row = m0 + sm * 16 + r16;
        okA[sm] = (row < M);
        abase[sm] = X + (size_t)(okA[sm] ? row : 0) * NFEAT + quad * 8;
    }

#pragma unroll 2
    for (int ks = 0; ks < 16; ++ks) {
        int ko = ks * 32;
        short8 bfr[4];
#pragma unroll
        for (int sn = 0; sn < 4; ++sn)
            bfr[sn] = *(const short8*)(wbase + (size_t)sn * 16 * NFEAT + ko);
#pragma unroll
        for (int sm = 0; sm < 4; ++sm) {
            short8 af;
            if (okA[sm]) {
                const float4* p = (const float4*)(abase[sm] + ko);
                float4 v0 = p[0], v1 = p[1];
                union { uint4 u; short8 s; } cv;
                cv.u.x = pack2(v0.x, v0.y);
                cv.u.y = pack2(v0.z, v0.w);
                cv.u.z = pack2(v1.x, v1.y);
                cv.u.w = pack2(v1.z, v1.w);
                af = cv.s;
            } else {
                af = (short8){0, 0, 0, 0, 0, 0, 0, 0};
            }
#pragma unroll
            for (int sn = 0; sn < 4; ++sn)
                acc[sm][sn] = __builtin_amdgcn_mfma_f32_16x16x32_bf16(
                    af, bfr[sn], acc[sm][sn], 0, 0, 0);
        }
    }
#pragma unroll
    for (int sm = 0; sm < 4; ++sm) {
#pragma unroll
        for (int rr = 0; rr < 4; ++rr) {
            int row = m0 + sm * 16 + quad * 4 + rr;
            if (row < M) {
                float dsc = dis[row];
#pragma unroll
                for (int sn = 0; sn < 4; ++sn) {
                    int col = wn * 64 + sn * 16 + r16;
                    H[(size_t)row * NHID + col] = f2bf(acc[sm][sn][rr] * dsc);
                }
            }
        }
    }
}

// ---------------- agg1 (feature-half pass): wave/node, 16-deep pipeline ----------------
// pass f0u in {0,64}: aggregates bf16 feature columns [2*f0u, 2*f0u+128).

__global__ __launch_bounds__(256) void agg1h_k(const unsigned short* __restrict__ Hb,
                                               const int* __restrict__ offs,
                                               const int* __restrict__ csrs,
                                               const float* __restrict__ dis,
                                               const float* __restrict__ b1,
                                               unsigned short* __restrict__ outb,
                                               int n, int f0u) {
    int lane = threadIdx.x & 63;
    int i = blockIdx.x * 4 + (threadIdx.x >> 6);
    if (i >= n) return;
    const unsigned* Hv = (const unsigned*)Hb;   // row = 128 uints (256 bf16)
    int col = f0u + lane;                        // uint column within row
    float a0 = 0.f, a1 = 0.f;
    int beg = offs[i], end = offs[i + 1];
    int e = beg;
    {
        int c[16]; unsigned g[16];
        for (; e + 16 <= end; e += 16) {
#pragma unroll
            for (int u = 0; u < 16; ++u) c[u] = csrs[e + u];
#pragma unroll
            for (int u = 0; u < 16; ++u) g[u] = Hv[(size_t)c[u] * 128 + col];
#pragma unroll
            for (int u = 0; u < 16; ++u) {
                a0 += bflo(g[u]); a1 += bfhi(g[u]);
            }
        }
        // masked batched tail: up to 15 edges, all gathers in flight at once
        if (e < end) {
#pragma unroll
            for (int u = 0; u < 16; ++u)
                c[u] = (e + u < end) ? csrs[e + u] : i;
#pragma unroll
            for (int u = 0; u < 16; ++u) g[u] = Hv[(size_t)c[u] * 128 + col];
#pragma unroll
            for (int u = 0; u < 16; ++u) {
                float sel = (e + u < end) ? 1.f : 0.f;
                a0 = fmaf(sel, bflo(g[u]), a0); a1 = fmaf(sel, bfhi(g[u]), a1);
            }
        }
    }
    // self loop: + H'[i]
    unsigned v = Hv[(size_t)i * 128 + col];
    a0 += bflo(v); a1 += bfhi(v);
    float di = dis[i];
    float2 bb = ((const float2*)b1)[col];
    a0 = fmaxf(fmaf(a0, di, bb.x), 0.f);
    a1 = fmaxf(fmaf(a1, di, bb.y), 0.f);
    ((unsigned*)outb)[(size_t)i * 128 + col] = pack2(a0, a1);
}

// ---------------- GEMM2 (MFMA): H2'(bf16, rows padded to 64) = dis[i] * (A · W2) -------
// 64 rows/block, 4 waves; wave = 16-row m-frag x 3 n-frags (48 cols, pad past 40).
// A-frags straight from global; W2 staged in LDS as bf16 hi+lo (fp32-accurate).

__global__ __launch_bounds__(256) void gemm2_k(const unsigned short* __restrict__ Ab,
                                               const unsigned short* __restrict__ WT2,
                                               const float* __restrict__ dis,
                                               unsigned short* __restrict__ H2b, int M) {
    __shared__ unsigned short wt2s[96][264];   // pitch 264: 2-way LDS aliasing only
    int t = threadIdx.x;
    int lane = t & 63;
    int w = t >> 6;          // 0..3
    int quad = lane >> 4;
    int r16 = lane & 15;
    // stage WT2 (96x256 bf16 = 48 hi rows + 48 lo rows)
    for (int idx = t; idx < 96 * 32; idx += 256) {
        int r = idx >> 5;
        int c = idx & 31;
        *(uint4*)&wt2s[r][c * 8] = ((const uint4*)(WT2 + (size_t)r * 256))[c];
    }
    __syncthreads();
    int row0 = blockIdx.x * 64 + w * 16;
    int gr = row0 + r16;
    f32x4 acc[3];
#pragma unroll
    for (int sn = 0; sn < 3; ++sn) acc[sn] = (f32x4){0.f, 0.f, 0.f, 0.f};
#pragma unroll
    for (int ks = 0; ks < 8; ++ks) {
        short8 af;
        if (gr < M)
            af = *(const short8*)(Ab + (size_t)gr * NHID + ks * 32 + quad * 8);
        else
            af = (short8){0, 0, 0, 0, 0, 0, 0, 0};
#pragma unroll
        for (int sn = 0; sn < 3; ++sn) {
            short8 bhi = *(const short8*)&wt2s[sn * 16 + r16][ks * 32 + quad * 8];
            short8 blo = *(const short8*)&wt2s[48 + sn * 16 + r16][ks * 32 + quad * 8];
            acc[sn] = __builtin_amdgcn_mfma_f32_16x16x32_bf16(af, bhi, acc[sn], 0, 0, 0);
            acc[sn] = __builtin_amdgcn_mfma_f32_16x16x32_bf16(af, blo, acc[sn], 0, 0, 0);
        }
    }
#pragma unroll
    for (int rr = 0; rr < 4; ++rr) {
        int row = row0 + quad * 4 + rr;
        if (row < M) {
            float dsc = dis[row];
#pragma unroll
            for (int sn = 0; sn < 3; ++sn)
                H2b[(size_t)row * 64 + sn * 16 + r16] = f2bf(acc[sn][rr] * dsc);
        }
    }
    // zero pad cols 48..63 (lanes 0..31: 16 rows x two 8-short segments)
    if (lane < 32) {
        int row = row0 + r16;
        if (row < M)
            *(uint4*)&H2b[(size_t)row * 64 + 48 + (lane >> 4) * 8] =
                make_uint4(0u, 0u, 0u, 0u);
    }
}

// ---------------- agg2 + bias + fused log_softmax ----------------
// wave per node; 4 slots x 16 lanes; each gather = exactly one 128-B line.
// 32-edge pipelined main batch + one masked batch for the <=31 remainder.

__global__ __launch_bounds__(256) void agg2_k(const unsigned short* __restrict__ H2b,
                                              const int* __restrict__ offs,
                                              const int* __restrict__ csrs,
                                              const float* __restrict__ dis,
                                              const float* __restrict__ b2,
                                              float* __restrict__ out, int n) {
    int lane = threadIdx.x & 63;
    int i = blockIdx.x * 4 + (threadIdx.x >> 6);
    if (i >= n) return;
    const uint2* Hv = (const uint2*)H2b;   // row = 16 uint2 (64 bf16, 40 real)
    int slot = lane >> 4;
    int r16 = lane & 15;
    float a0 = 0.f, a1 = 0.f, a2 = 0.f, a3 = 0.f;
    int beg = offs[i], end = offs[i + 1];
    int e = beg;
    {
        int c[8]; uint2 g[8];
        for (; e + 32 <= end; e += 32) {
#pragma unroll
            for (int u = 0; u < 8; ++u) c[u] = csrs[e + u * 4 + slot];
#pragma unroll
            for (int u = 0; u < 8; ++u) g[u] = Hv[(size_t)c[u] * 16 + r16];
#pragma unroll
            for (int u = 0; u < 8; ++u) {
                a0 += bflo(g[u].x); a1 += bfhi(g[u].x);
                a2 += bflo(g[u].y); a3 += bfhi(g[u].y);
            }
        }
        // masked batched tail: up to 31 edges
        if (e < end) {
#pragma unroll
            for (int u = 0; u < 8; ++u) {
                int idx = e + u * 4 + slot;
                c[u] = (idx < end) ? csrs[idx] : i;
            }
#pragma unroll
            for (int u = 0; u < 8; ++u) g[u] = Hv[(size_t)c[u] * 16 + r16];
#pragma unroll
            for (int u = 0; u < 8; ++u) {
                float sel = (e + u * 4 + slot < end) ? 1.f : 0.f;
                a0 = fmaf(sel, bflo(g[u].x), a0); a1 = fmaf(sel, bfhi(g[u].x), a1);
                a2 = fmaf(sel, bflo(g[u].y), a2); a3 = fmaf(sel, bfhi(g[u].y), a3);
            }
        }
    }
    // self loop (add once, in slot 0)
    if (slot == 0) {
        uint2 v = Hv[(size_t)i * 16 + r16];
        a0 += bflo(v.x); a1 += bfhi(v.x);
        a2 += bflo(v.y); a3 += bfhi(v.y);
    }
    // fold the 4 slots together: after xor16+xor32 every lane holds the total
    a0 += __shfl_xor(a0, 16, 64); a0 += __shfl_xor(a0, 32, 64);
    a1 += __shfl_xor(a1, 16, 64); a1 += __shfl_xor(a1, 32, 64);
    a2 += __shfl_xor(a2, 16, 64); a2 += __shfl_xor(a2, 32, 64);
    a3 += __shfl_xor(a3, 16, 64); a3 += __shfl_xor(a3, 32, 64);
    float di = dis[i];
    bool act = (r16 < 10);  // lanes holding real features (4*r16 < 40)
    float4 bb = act ? ((const float4*)b2)[r16] : make_float4(0.f, 0.f, 0.f, 0.f);
    a0 = fmaf(a0, di, bb.x); a1 = fmaf(a1, di, bb.y);
    a2 = fmaf(a2, di, bb.z); a3 = fmaf(a3, di, bb.w);
    float m = act ? fmaxf(fmaxf(a0, a1), fmaxf(a2, a3)) : -INFINITY;
#pragma unroll
    for (int off = 8; off > 0; off >>= 1) m = fmaxf(m, __shfl_xor(m, off, 16));
    float s = act ? (expf(a0 - m) + expf(a1 - m) + expf(a2 - m) + expf(a3 - m)) : 0.f;
#pragma unroll
    for (int off = 8; off > 0; off >>= 1) s += __shfl_xor(s, off, 16);
    float ls = m + logf(s);
    if (lane < 10) {
        float4 o = make_float4(a0 - ls, a1 - ls, a2 - ls, a3 - ls);
        ((float4*)(out + (size_t)i * NCLASS))[lane] = o;
    }
}

// ---------------- launch ----------------

extern "C" void kernel_launch(void* const* d_in, const int* in_sizes, int n_in,
                              void* d_out, int out_size, void* d_ws, size_t ws_size,
                              hipStream_t stream) {
    const float* x  = (const float*)d_in[0];
    const float* W1 = (const float*)d_in[1];
    const float* b1 = (const float*)d_in[2];
    const float* W2 = (const float*)d_in[3];
    const float* b2 = (const float*)d_in[4];
    const int*   ei = (const int*)d_in[5];   // int32-staged

    const int N = in_sizes[0] / NFEAT;      // 100000
    const int E = in_sizes[5] / 2;          // 3200000

    size_t off = 0;
    auto alloc = [&](size_t bytes) { size_t o = off; off += (bytes + 255) & ~(size_t)255; return o; };
    char* ws = (char*)d_ws;
    int*            offs    = (int*)           (ws + alloc((size_t)(N + 1) * 4));
    float*          dis     = (float*)         (ws + alloc((size_t)N * 4));
    int*            bcnt    = (int*)           (ws + alloc((size_t)NBUCK * 4));
    int*            bbase   = (int*)           (ws + alloc((size_t)NBUCK * 4));
    unsigned*       binned  = (unsigned*)      (ws + alloc((size_t)NBUCK * BCAP * 4));
    int*            csrs    = (int*)           (ws + alloc((size_t)E * 4));
    unsigned short* wT      = (unsigned short*)(ws + alloc((size_t)NFEAT * NHID * 2));
    unsigned short* wT2     = (unsigned short*)(ws + alloc((size_t)96 * 256 * 2));
    unsigned short* h1b     = (unsigned short*)(ws + alloc((size_t)N * NHID * 2));
    unsigned short* a1b     = (unsigned short*)(ws + alloc((size_t)N * NHID * 2));
    unsigned short* h2b     = (unsigned short*)(ws + alloc((size_t)N * 64 * 2));
    float*          out     = (float*)d_out;

    int npart = (E + PCHUNK - 1) / PCHUNK;

    hipMemsetAsync(bcnt, 0, (size_t)NBUCK * 4, stream);
    partcast_k<<<(NFEAT * NHID) / 256 + 1 + npart, 256, 0, stream>>>(W1, wT, W2, wT2, ei,
                                                                     bcnt, binned, E);
    bscan_k<<<1, 1024, 0, stream>>>(bcnt, bbase, offs, N, E);
    fill2_k<<<NBUCK, 512, 0, stream>>>(binned, bcnt, bbase, offs, dis, csrs, N);
    gemm1_k<<<(N + 127) / 128, 512, 0, stream>>>(x, wT, dis, h1b, N);
    agg1h_k<<<(N + 3) / 4, 256, 0, stream>>>(h1b, offs, csrs, dis, b1, a1b, N, 0);
    agg1h_k<<<(N + 3) / 4, 256, 0, stream>>>(h1b, offs, csrs, dis, b1, a1b, N, 64);
    gemm2_k<<<(N + 63) / 64, 256, 0, stream>>>(a1b, wT2, dis, h2b, N);
    agg2_k<<<(N + 3) / 4, 256, 0, stream>>>(h2b, offs, csrs, dis, b2, out, N);
}

// Round 12
// 706.048 us; speedup vs baseline: 1.1497x; 1.1497x over previous
//
#include <hip/hip_runtime.h>
#include <math.h>

#define NFEAT 512
#define NHID  256
#define NCLASS 40
#define NBUCK 782        // ceil(100000 / 128) dst-buckets of 128 nodes
#define BCAP  5120       // bucket capacity: mean 4096 + ~16 sigma
#define PCHUNK 8192      // edges per partition block (LDS-staged)

typedef __attribute__((ext_vector_type(8))) short short8;
typedef __attribute__((ext_vector_type(4))) float f32x4;

// ---------------- bf16 helpers ----------------

__device__ __forceinline__ float bflo(unsigned u) {
    union { unsigned i; float f; } x; x.i = u << 16; return x.f;
}
__device__ __forceinline__ float bfhi(unsigned u) {
    union { unsigned i; float f; } x; x.i = u & 0xffff0000u; return x.f;
}
__device__ __forceinline__ unsigned short f2bf(float f) {
    union { float f; unsigned i; } x; x.f = f;
    unsigned r = x.i + 0x7fffu + ((x.i >> 16) & 1u);   // round-to-nearest-even
    return (unsigned short)(r >> 16);
}
__device__ __forceinline__ float bf2f(unsigned short h) {
    union { unsigned i; float f; } x; x.i = (unsigned)h << 16; return x.f;
}
__device__ __forceinline__ unsigned pack2(float a, float b) {
    return (unsigned)f2bf(a) | ((unsigned)f2bf(b) << 16);
}

// ---------------- fused: W1 cast -> fragment-major WTsw (blocks 0..63) ∥
// W2 hi/lo cast (block 64) ∥ LDS-staged edge partition (rest).
// WTsw layout: fragment (nblk,kblk): lane l=(quad*16+r16), elem j holds
// W1[k = kblk*32+quad*8+j][col = nblk*16+r16]  -> a wave's B-fragment read is
// 64 lanes x consecutive 16 B = one contiguous 1 KB L2-resident read.
// Partition: hist -> block scan -> bucket-major LDS staging -> per-bucket global
// reservation -> wave-per-bucket coalesced flush. Entry: (src<<7)|(dst&127).

__global__ __launch_bounds__(256) void partcast_k(const float* __restrict__ W1,
                                                  unsigned short* __restrict__ WTsw,
                                                  const float* __restrict__ W2,
                                                  unsigned short* __restrict__ WT2,
                                                  const int* __restrict__ ei,
                                                  int* bucketCnt,
                                                  unsigned* __restrict__ binned, int E) {
    __shared__ unsigned staged[PCHUNK];
    __shared__ int hist[NBUCK];
    __shared__ int lofs[NBUCK];
    __shared__ int sbase[NBUCK];
    __shared__ int lcur[NBUCK];
    __shared__ int wsum[256];
    int bid = blockIdx.x;
    int t = threadIdx.x;
    if (bid < 64) {
        // thread -> (nn, k8): one 16-B fragment chunk (8 consecutive k)
        int tid = bid * 256 + t;
        int nn = tid >> 6;           // 0..255 (output col)
        int k8 = tid & 63;           // 0..63  (k>>3)
        unsigned short buf[8];
#pragma unroll
        for (int j = 0; j < 8; ++j)
            buf[j] = f2bf(W1[(size_t)(k8 * 8 + j) * NHID + nn]);
        size_t dst = ((size_t)((nn >> 4) * 16 + (k8 >> 2)) * 64 +
                      (k8 & 3) * 16 + (nn & 15)) * 8;
        *(uint4*)(WTsw + dst) = *(const uint4*)buf;
        return;
    }
    if (bid == 64) {
        // W2 -> col-major bf16 hi/lo split: WT2[j][k] (j<48 hi, j>=48 lo), 48 cols padded
        for (int idx = t; idx < 96 * 256; idx += 256) {
            int j2 = idx >> 8;           // 0..95
            int k = idx & 255;
            int j = (j2 < 48) ? j2 : j2 - 48;
            float v = (j < NCLASS) ? W2[k * NCLASS + j] : 0.f;
            unsigned short hi = f2bf(v);
            WT2[idx] = (j2 < 48) ? hi : f2bf(v - bf2f(hi));
        }
        return;
    }
    int pb = bid - 65;
    int beg = pb * PCHUNK;
    int end = beg + PCHUNK; if (end > E) end = E;

    for (int b = t; b < NBUCK; b += 256) hist[b] = 0;
    __syncthreads();
    // phase 1: histogram
    for (int e = beg + t; e < end; e += 256) {
        int d = ei[(size_t)E + e];
        atomicAdd(&hist[d >> 7], 1);
    }
    __syncthreads();
    // phase 2: exclusive scan over 782 bucket counts (256 threads x 4)
    int v[4];
    int s0 = 0;
#pragma unroll
    for (int r = 0; r < 4; ++r) {
        int idx = t * 4 + r;
        v[r] = (idx < NBUCK) ? hist[idx] : 0;
        s0 += v[r];
    }
    wsum[t] = s0;
    __syncthreads();
    for (int off = 1; off < 256; off <<= 1) {
        int add = (t >= off) ? wsum[t - off] : 0;
        __syncthreads();
        wsum[t] += add;
        __syncthreads();
    }
    int excl = wsum[t] - s0;
#pragma unroll
    for (int r = 0; r < 4; ++r) {
        int idx = t * 4 + r;
        if (idx < NBUCK) { lofs[idx] = excl; lcur[idx] = excl; }
        excl += v[r];
    }
    __syncthreads();
    // phase 3a: global reservation per bucket
    for (int b = t; b < NBUCK; b += 256) {
        int h = hist[b];
        if (h) sbase[b] = atomicAdd(&bucketCnt[b], h);
    }
    // phase 3b: re-read chunk (L2-warm), scatter bucket-major into LDS
    for (int e = beg + t; e < end; e += 256) {
        int s = ei[e];
        int d = ei[(size_t)E + e];
        int b = d >> 7;
        int p = atomicAdd(&lcur[b], 1);
        staged[p] = ((unsigned)s << 7) | (unsigned)(d & 127);
    }
    __syncthreads();
    // phase 4: coalesced flush, wave-per-bucket round-robin
    int w = t >> 6, lane = t & 63;
    for (int b = w; b < NBUCK; b += 4) {
        int h = hist[b];
        if (!h) continue;
        int lo = lofs[b];
        size_t gb = (size_t)b * BCAP + sbase[b];
        for (int l = lane; l < h; l += 64)
            binned[gb + l] = staged[lo + l];
    }
}

// ---------------- exclusive scan over 782 bucket counts -> bucket bases ----------------

__global__ __launch_bounds__(1024) void bscan_k(const int* __restrict__ bucketCnt,
                                                int* __restrict__ bbase,
                                                int* __restrict__ offs, int n, int E) {
    __shared__ int sd[1024];
    int t = threadIdx.x;
    int v = (t < NBUCK) ? bucketCnt[t] : 0;
    sd[t] = v;
    __syncthreads();
    for (int off = 1; off < 1024; off <<= 1) {
        int add = (t >= off) ? sd[t - off] : 0;
        __syncthreads();
        sd[t] += add;
        __syncthreads();
    }
    if (t < NBUCK) bbase[t] = sd[t] - v;
    if (t == 0) offs[n] = E;
}

// ---------------- bucket-local CSR fill: per-node hist + scan + offs + dis + scatter ----

__global__ __launch_bounds__(512) void fill2_k(const unsigned* __restrict__ binned,
                                               const int* __restrict__ bucketCnt,
                                               const int* __restrict__ bbase,
                                               int* __restrict__ offs,
                                               float* __restrict__ dis,
                                               int* __restrict__ csrs, int n) {
    __shared__ int h128[128];
    __shared__ int sd[128];
    __shared__ int lcur[128];
    int b = blockIdx.x;
    int t = threadIdx.x;
    int node0 = b << 7;
    int cbt = bucketCnt[b];
    size_t base_in = (size_t)b * BCAP;
    int gbase = bbase[b];
    if (t < 128) h128[t] = 0;
    __syncthreads();
    for (int e = t; e < cbt; e += 512) {
        unsigned u = binned[base_in + e];
        atomicAdd(&h128[u & 127], 1);
    }
    __syncthreads();
    int v = (t < 128) ? h128[t] : 0;
    if (t < 128) sd[t] = v;
    __syncthreads();
    for (int off = 1; off < 128; off <<= 1) {
        int add = (t < 128 && t >= off) ? sd[t - off] : 0;
        __syncthreads();
        if (t < 128) sd[t] += add;
        __syncthreads();
    }
    if (t < 128) {
        int excl = sd[t] - v;
        int nd = node0 + t;
        if (nd < n) {
            offs[nd] = gbase + excl;
            dis[nd] = rsqrtf((float)v + 1.0f);   // +1 self loop
        }
        lcur[t] = gbase + excl;
    }
    __syncthreads();
    for (int e = t; e < cbt; e += 512) {
        unsigned u = binned[base_in + e];
        int pos = atomicAdd(&lcur[u & 127], 1);
        csrs[pos] = (int)(u >> 7);
    }
}

// ---------------- GEMM1: H'(bf16) = dis[i] * (X fp32→bf16 · W1), MFMA ----------------
// 128 rows x 256 cols per block, 512 threads = 8 waves (2M x 4N), 64x64 per wave.
// A staged in LDS (round-10 path, verified); B read directly from fragment-major
// WTsw in L2 — one coalesced 1 KB wave-read per fragment (fixes round-11's
// 64-line scatter that saturated the memory-request pipe).

__global__ __launch_bounds__(512) void gemm1_k(const float* __restrict__ X,
                                               const unsigned short* __restrict__ WTsw,
                                               const float* __restrict__ dis,
                                               unsigned short* __restrict__ H, int M) {
    __shared__ unsigned short as[128][72];
    int t = threadIdx.x;
    int lane = t & 63;
    int w = t >> 6;          // 0..7
    int wm = w >> 2;         // 0..1
    int wn = w & 3;          // 0..3
    int m0 = blockIdx.x * 128;
    int quad = lane >> 4;
    int r16 = lane & 15;

    f32x4 acc[4][4];
#pragma unroll
    for (int a = 0; a < 4; ++a)
#pragma unroll
        for (int b = 0; b < 4; ++b) acc[a][b] = (f32x4){0.f, 0.f, 0.f, 0.f};

    for (int k0 = 0; k0 < NFEAT; k0 += 64) {
        {
            // A tile: 128 rows x 64 cols, thread -> (row = t>>2, colgroup = t&3)
            int m = t >> 2;
            int c = (t & 3) * 16;
            int gi = m0 + m;
            float4 v0, v1, v2, v3;
            if (gi < M) {
                const float4* p = (const float4*)(X + (size_t)gi * NFEAT + k0 + c);
                v0 = p[0]; v1 = p[1]; v2 = p[2]; v3 = p[3];
            } else {
                v0 = v1 = v2 = v3 = make_float4(0.f, 0.f, 0.f, 0.f);
            }
            uint4 p0, p1;
            p0.x = pack2(v0.x, v0.y); p0.y = pack2(v0.z, v0.w);
            p0.z = pack2(v1.x, v1.y); p0.w = pack2(v1.z, v1.w);
            p1.x = pack2(v2.x, v2.y); p1.y = pack2(v2.z, v2.w);
            p1.z = pack2(v3.x, v3.y); p1.w = pack2(v3.z, v3.w);
            *(uint4*)&as[m][c] = p0;
            *(uint4*)&as[m][c + 8] = p1;
        }
        __syncthreads();
        int kb0 = k0 >> 5;   // first of 2 kblks in this tile
#pragma unroll
        for (int ks = 0; ks < 2; ++ks) {
            int kblk = kb0 + ks;
            short8 af[4], bfr[4];
#pragma unroll
            for (int sm = 0; sm < 4; ++sm)
                af[sm] = *(const short8*)&as[wm * 64 + sm * 16 + r16][ks * 32 + quad * 8];
#pragma unroll
            for (int sn = 0; sn < 4; ++sn)
                bfr[sn] = *(const short8*)(WTsw +
                    ((size_t)((wn * 4 + sn) * 16 + kblk) * 64 + lane) * 8);
#pragma unroll
            for (int sm = 0; sm < 4; ++sm)
#pragma unroll
                for (int sn = 0; sn < 4; ++sn)
                    acc[sm][sn] = __builtin_amdgcn_mfma_f32_16x16x32_bf16(
                        af[sm], bfr[sn], acc[sm][sn], 0, 0, 0);
        }
        __syncthreads();
    }
#pragma unroll
    for (int sm = 0; sm < 4; ++sm) {
#pragma unroll
        for (int rr = 0; rr < 4; ++rr) {
            int row = m0 + wm * 64 + sm * 16 + quad * 4 + rr;
            if (row < M) {
                float dsc = dis[row];
#pragma unroll
                for (int sn = 0; sn < 4; ++sn) {
                    int col = wn * 64 + sn * 16 + r16;
                    H[(size_t)row * NHID + col] = f2bf(acc[sm][sn][rr] * dsc);
                }
            }
        }
    }
}

// ---------------- agg1 (feature-half pass): wave/node, 16-deep pipeline ----------------
// pass f0u in {0,64}: aggregates bf16 feature columns [2*f0u, 2*f0u+128).

__global__ __launch_bounds__(256) void agg1h_k(const unsigned short* __restrict__ Hb,
                                               const int* __restrict__ offs,
                                               const int* __restrict__ csrs,
                                               const float* __restrict__ dis,
                                               const float* __restrict__ b1,
                                               unsigned short* __restrict__ outb,
                                               int n, int f0u) {
    int lane = threadIdx.x & 63;
    int i = blockIdx.x * 4 + (threadIdx.x >> 6);
    if (i >= n) return;
    const unsigned* Hv = (const unsigned*)Hb;   // row = 128 uints (256 bf16)
    int col = f0u + lane;                        // uint column within row
    float a0 = 0.f, a1 = 0.f;
    int beg = offs[i], end = offs[i + 1];
    int e = beg;
    {
        int c[16]; unsigned g[16];
        for (; e + 16 <= end; e += 16) {
#pragma unroll
            for (int u = 0; u < 16; ++u) c[u] = csrs[e + u];
#pragma unroll
            for (int u = 0; u < 16; ++u) g[u] = Hv[(size_t)c[u] * 128 + col];
#pragma unroll
            for (int u = 0; u < 16; ++u) {
                a0 += bflo(g[u]); a1 += bfhi(g[u]);
            }
        }
        // masked batched tail: up to 15 edges, all gathers in flight at once
        if (e < end) {
#pragma unroll
            for (int u = 0; u < 16; ++u)
                c[u] = (e + u < end) ? csrs[e + u] : i;
#pragma unroll
            for (int u = 0; u < 16; ++u) g[u] = Hv[(size_t)c[u] * 128 + col];
#pragma unroll
            for (int u = 0; u < 16; ++u) {
                float sel = (e + u < end) ? 1.f : 0.f;
                a0 = fmaf(sel, bflo(g[u]), a0); a1 = fmaf(sel, bfhi(g[u]), a1);
            }
        }
    }
    // self loop: + H'[i]
    unsigned v = Hv[(size_t)i * 128 + col];
    a0 += bflo(v); a1 += bfhi(v);
    float di = dis[i];
    float2 bb = ((const float2*)b1)[col];
    a0 = fmaxf(fmaf(a0, di, bb.x), 0.f);
    a1 = fmaxf(fmaf(a1, di, bb.y), 0.f);
    ((unsigned*)outb)[(size_t)i * 128 + col] = pack2(a0, a1);
}

// ---------------- GEMM2 (MFMA): H2'(bf16, rows padded to 64) = dis[i] * (A · W2) -------
// 64 rows/block, 4 waves; wave = 16-row m-frag x 3 n-frags (48 cols, pad past 40).
// A-frags straight from global; W2 staged in LDS as bf16 hi+lo (fp32-accurate).

__global__ __launch_bounds__(256) void gemm2_k(const unsigned short* __restrict__ Ab,
                                               const unsigned short* __restrict__ WT2,
                                               const float* __restrict__ dis,
                                               unsigned short* __restrict__ H2b, int M) {
    __shared__ unsigned short wt2s[96][264];   // pitch 264: 2-way LDS aliasing only
    int t = threadIdx.x;
    int lane = t & 63;
    int w = t >> 6;          // 0..3
    int quad = lane >> 4;
    int r16 = lane & 15;
    // stage WT2 (96x256 bf16 = 48 hi rows + 48 lo rows)
    for (int idx = t; idx < 96 * 32; idx += 256) {
        int r = idx >> 5;
        int c = idx & 31;
        *(uint4*)&wt2s[r][c * 8] = ((const uint4*)(WT2 + (size_t)r * 256))[c];
    }
    __syncthreads();
    int row0 = blockIdx.x * 64 + w * 16;
    int gr = row0 + r16;
    f32x4 acc[3];
#pragma unroll
    for (int sn = 0; sn < 3; ++sn) acc[sn] = (f32x4){0.f, 0.f, 0.f, 0.f};
#pragma unroll
    for (int ks = 0; ks < 8; ++ks) {
        short8 af;
        if (gr < M)
            af = *(const short8*)(Ab + (size_t)gr * NHID + ks * 32 + quad * 8);
        else
            af = (short8){0, 0, 0, 0, 0, 0, 0, 0};
#pragma unroll
        for (int sn = 0; sn < 3; ++sn) {
            short8 bhi = *(const short8*)&wt2s[sn * 16 + r16][ks * 32 + quad * 8];
            short8 blo = *(const short8*)&wt2s[48 + sn * 16 + r16][ks * 32 + quad * 8];
            acc[sn] = __builtin_amdgcn_mfma_f32_16x16x32_bf16(af, bhi, acc[sn], 0, 0, 0);
            acc[sn] = __builtin_amdgcn_mfma_f32_16x16x32_bf16(af, blo, acc[sn], 0, 0, 0);
        }
    }
#pragma unroll
    for (int rr = 0; rr < 4; ++rr) {
        int row = row0 + quad * 4 + rr;
        if (row < M) {
            float dsc = dis[row];
#pragma unroll
            for (int sn = 0; sn < 3; ++sn)
                H2b[(size_t)row * 64 + sn * 16 + r16] = f2bf(acc[sn][rr] * dsc);
        }
    }
    // zero pad cols 48..63 (lanes 0..31: 16 rows x two 8-short segments)
    if (lane < 32) {
        int row = row0 + r16;
        if (row < M)
            *(uint4*)&H2b[(size_t)row * 64 + 48 + (lane >> 4) * 8] =
                make_uint4(0u, 0u, 0u, 0u);
    }
}

// ---------------- agg2 + bias + fused log_softmax ----------------
// wave per node; 4 slots x 16 lanes; each gather = exactly one 128-B line.
// 32-edge pipelined main batch + one masked batch for the <=31 remainder.

__global__ __launch_bounds__(256) void agg2_k(const unsigned short* __restrict__ H2b,
                                              const int* __restrict__ offs,
                                              const int* __restrict__ csrs,
                                              const float* __restrict__ dis,
                                              const float* __restrict__ b2,
                                              float* __restrict__ out, int n) {
    int lane = threadIdx.x & 63;
    int i = blockIdx.x * 4 + (threadIdx.x >> 6);
    if (i >= n) return;
    const uint2* Hv = (const uint2*)H2b;   // row = 16 uint2 (64 bf16, 40 real)
    int slot = lane >> 4;
    int r16 = lane & 15;
    float a0 = 0.f, a1 = 0.f, a2 = 0.f, a3 = 0.f;
    int beg = offs[i], end = offs[i + 1];
    int e = beg;
    {
        int c[8]; uint2 g[8];
        for (; e + 32 <= end; e += 32) {
#pragma unroll
            for (int u = 0; u < 8; ++u) c[u] = csrs[e + u * 4 + slot];
#pragma unroll
            for (int u = 0; u < 8; ++u) g[u] = Hv[(size_t)c[u] * 16 + r16];
#pragma unroll
            for (int u = 0; u < 8; ++u) {
                a0 += bflo(g[u].x); a1 += bfhi(g[u].x);
                a2 += bflo(g[u].y); a3 += bfhi(g[u].y);
            }
        }
        // masked batched tail: up to 31 edges
        if (e < end) {
#pragma unroll
            for (int u = 0; u < 8; ++u) {
                int idx = e + u * 4 + slot;
                c[u] = (idx < end) ? csrs[idx] : i;
            }
#pragma unroll
            for (int u = 0; u < 8; ++u) g[u] = Hv[(size_t)c[u] * 16 + r16];
#pragma unroll
            for (int u = 0; u < 8; ++u) {
                float sel = (e + u * 4 + slot < end) ? 1.f : 0.f;
                a0 = fmaf(sel, bflo(g[u].x), a0); a1 = fmaf(sel, bfhi(g[u].x), a1);
                a2 = fmaf(sel, bflo(g[u].y), a2); a3 = fmaf(sel, bfhi(g[u].y), a3);
            }
        }
    }
    // self loop (add once, in slot 0)
    if (slot == 0) {
        uint2 v = Hv[(size_t)i * 16 + r16];
        a0 += bflo(v.x); a1 += bfhi(v.x);
        a2 += bflo(v.y); a3 += bfhi(v.y);
    }
    // fold the 4 slots together: after xor16+xor32 every lane holds the total
    a0 += __shfl_xor(a0, 16, 64); a0 += __shfl_xor(a0, 32, 64);
    a1 += __shfl_xor(a1, 16, 64); a1 += __shfl_xor(a1, 32, 64);
    a2 += __shfl_xor(a2, 16, 64); a2 += __shfl_xor(a2, 32, 64);
    a3 += __shfl_xor(a3, 16, 64); a3 += __shfl_xor(a3, 32, 64);
    float di = dis[i];
    bool act = (r16 < 10);  // lanes holding real features (4*r16 < 40)
    float4 bb = act ? ((const float4*)b2)[r16] : make_float4(0.f, 0.f, 0.f, 0.f);
    a0 = fmaf(a0, di, bb.x); a1 = fmaf(a1, di, bb.y);
    a2 = fmaf(a2, di, bb.z); a3 = fmaf(a3, di, bb.w);
    float m = act ? fmaxf(fmaxf(a0, a1), fmaxf(a2, a3)) : -INFINITY;
#pragma unroll
    for (int off = 8; off > 0; off >>= 1) m = fmaxf(m, __shfl_xor(m, off, 16));
    float s = act ? (expf(a0 - m) + expf(a1 - m) + expf(a2 - m) + expf(a3 - m)) : 0.f;
#pragma unroll
    for (int off = 8; off > 0; off >>= 1) s += __shfl_xor(s, off, 16);
    float ls = m + logf(s);
    if (lane < 10) {
        float4 o = make_float4(a0 - ls, a1 - ls, a2 - ls, a3 - ls);
        ((float4*)(out + (size_t)i * NCLASS))[lane] = o;
    }
}

// ---------------- launch ----------------

extern "C" void kernel_launch(void* const* d_in, const int* in_sizes, int n_in,
                              void* d_out, int out_size, void* d_ws, size_t ws_size,
                              hipStream_t stream) {
    const float* x  = (const float*)d_in[0];
    const float* W1 = (const float*)d_in[1];
    const float* b1 = (const float*)d_in[2];
    const float* W2 = (const float*)d_in[3];
    const float* b2 = (const float*)d_in[4];
    const int*   ei = (const int*)d_in[5];   // int32-staged

    const int N = in_sizes[0] / NFEAT;      // 100000
    const int E = in_sizes[5] / 2;          // 3200000

    size_t off = 0;
    auto alloc = [&](size_t bytes) { size_t o = off; off += (bytes + 255) & ~(size_t)255; return o; };
    char* ws = (char*)d_ws;
    int*            offs    = (int*)           (ws + alloc((size_t)(N + 1) * 4));
    float*          dis     = (float*)         (ws + alloc((size_t)N * 4));
    int*            bcnt    = (int*)           (ws + alloc((size_t)NBUCK * 4));
    int*            bbase   = (int*)           (ws + alloc((size_t)NBUCK * 4));
    unsigned*       binned  = (unsigned*)      (ws + alloc((size_t)NBUCK * BCAP * 4));
    int*            csrs    = (int*)           (ws + alloc((size_t)E * 4));
    unsigned short* wTsw    = (unsigned short*)(ws + alloc((size_t)NFEAT * NHID * 2));
    unsigned short* wT2     = (unsigned short*)(ws + alloc((size_t)96 * 256 * 2));
    unsigned short* h1b     = (unsigned short*)(ws + alloc((size_t)N * NHID * 2));
    unsigned short* a1b     = (unsigned short*)(ws + alloc((size_t)N * NHID * 2));
    unsigned short* h2b     = (unsigned short*)(ws + alloc((size_t)N * 64 * 2));
    float*          out     = (float*)d_out;

    int npart = (E + PCHUNK - 1) / PCHUNK;

    hipMemsetAsync(bcnt, 0, (size_t)NBUCK * 4, stream);
    partcast_k<<<65 + npart, 256, 0, stream>>>(W1, wTsw, W2, wT2, ei, bcnt, binned, E);
    bscan_k<<<1, 1024, 0, stream>>>(bcnt, bbase, offs, N, E);
    fill2_k<<<NBUCK, 512, 0, stream>>>(binned, bcnt, bbase, offs, dis, csrs, N);
    gemm1_k<<<(N + 127) / 128, 512, 0, stream>>>(x, wTsw, dis, h1b, N);
    agg1h_k<<<(N + 3) / 4, 256, 0, stream>>>(h1b, offs, csrs, dis, b1, a1b, N, 0);
    agg1h_k<<<(N + 3) / 4, 256, 0, stream>>>(h1b, offs, csrs, dis, b1, a1b, N, 64);
    gemm2_k<<<(N + 63) / 64, 256, 0, stream>>>(a1b, wT2, dis, h2b, N);
    agg2_k<<<(N + 3) / 4, 256, 0, stream>>>(h2b, offs, csrs, dis, b2, out, N);
}